// Round 5
// baseline (826.573 us; speedup 1.0000x reference)
//
#include <hip/hip_runtime.h>

#define N_NODES 100000
#define N_EDGES 1600000
#define NB 782      // ceil(N_NODES/128) buckets of 128 dst nodes
#define BSTRIDE 32  // ints per atomic counter slot (128 B) -- kills false sharing

typedef __attribute__((ext_vector_type(8))) short short8;
typedef __attribute__((ext_vector_type(4))) float float4e;

// async 16B global->LDS copy (lane-contiguous LDS dest)
#define GLDS16(g, l)                                                   \
  __builtin_amdgcn_global_load_lds(                                    \
      (const __attribute__((address_space(1))) unsigned int*)(g),      \
      (__attribute__((address_space(3))) unsigned int*)(l), 16, 0, 0)

// ---------------------------------------------------------------------------
// bf16 split helpers (RNE)
// ---------------------------------------------------------------------------
__device__ __forceinline__ unsigned short f2bf(float f) {
  unsigned u = __float_as_uint(f);
  u += 0x7FFFu + ((u >> 16) & 1u);
  return (unsigned short)(u >> 16);
}
__device__ __forceinline__ float bf2f(unsigned short h) {
  return __uint_as_float(((unsigned)h) << 16);
}

// ===========================================================================
// Bucketed CSR build (scratch in d_out, dead before final GEMM).
//   bucket b = dst >> 7 (128 nodes each). packed edge = (src<<7)|(dst&127).
//   All global atomic counters padded to 1 per 128B line (BSTRIDE).
// ===========================================================================
__global__ __launch_bounds__(256) void bucketHist_k(const int* __restrict__ dst,
                                                    int* __restrict__ bucketCnt,
                                                    int nE) {
  __shared__ int h[1024];
  for (int j = threadIdx.x; j < 1024; j += 256) h[j] = 0;
  __syncthreads();
  const int stride = gridDim.x * 256;
  for (int i = blockIdx.x * 256 + threadIdx.x; i < nE; i += stride)
    atomicAdd(&h[dst[i] >> 7], 1);
  __syncthreads();
  for (int j = threadIdx.x; j < NB; j += 256) {
    int v = h[j];
    if (v) atomicAdd(&bucketCnt[j * BSTRIDE], v);
  }
}

// single-block exclusive scan of bucket counts -> bucketStart[0..NB], cursor copy
__global__ __launch_bounds__(1024) void scanB_k(const int* __restrict__ bucketCnt,
                                                int* __restrict__ bucketStart,
                                                int* __restrict__ bucketCursor) {
  __shared__ int sm[1024];
  const int tid = threadIdx.x;
  int v = (tid < NB) ? bucketCnt[tid * BSTRIDE] : 0;
  sm[tid] = v;
  __syncthreads();
  for (int off = 1; off < 1024; off <<= 1) {
    int t = (tid >= off) ? sm[tid - off] : 0;
    __syncthreads();
    sm[tid] += t;
    __syncthreads();
  }
  if (tid < NB) {
    int excl = sm[tid] - v;
    bucketStart[tid] = excl;
    bucketCursor[tid * BSTRIDE] = excl;
  }
  if (tid == NB - 1) bucketStart[NB] = sm[tid];
}

__global__ __launch_bounds__(256) void bucketScatter_k(
    const int* __restrict__ src, const int* __restrict__ dst,
    int* __restrict__ bucketCursor, unsigned int* __restrict__ packed, int nE) {
  int i = blockIdx.x * 256 + threadIdx.x;
  if (i < nE) {
    int d = dst[i];
    int p = atomicAdd(&bucketCursor[(d >> 7) * BSTRIDE], 1);
    packed[p] = ((unsigned)src[i] << 7) | (unsigned)(d & 127);
  }
}

// one block per bucket: LDS node-count + local scan -> rowEnd; LDS-cursor
// scatter of sortedSrc confined to this bucket's contiguous CSR range.
__global__ __launch_bounds__(256) void fillB_k(
    const int* __restrict__ bucketStart, const unsigned int* __restrict__ packed,
    int* __restrict__ rowEnd, int* __restrict__ sortedSrc, int nNodes) {
  __shared__ int cnt[128];
  __shared__ int cur[128];
  const int b = blockIdx.x;
  const int tid = threadIdx.x;
  const int s0 = bucketStart[b];
  const int ne = bucketStart[b + 1] - s0;
  if (tid < 128) cnt[tid] = 0;
  __syncthreads();
  for (int i = tid; i < ne; i += 256)
    atomicAdd(&cnt[packed[s0 + i] & 127u], 1);
  __syncthreads();
  int v = (tid < 128) ? cnt[tid] : 0;
  // Hillis-Steele inclusive scan over 128 (all threads hit both barriers)
  for (int off = 1; off < 128; off <<= 1) {
    int t = (tid < 128 && tid >= off) ? cnt[tid - off] : 0;
    __syncthreads();
    if (tid < 128) cnt[tid] += t;
    __syncthreads();
  }
  if (tid < 128) {
    cur[tid] = s0 + cnt[tid] - v;  // exclusive start for this node
    int node = b * 128 + tid;
    if (node < nNodes) rowEnd[node] = s0 + cnt[tid];
  }
  __syncthreads();
  for (int i = tid; i < ne; i += 256) {
    unsigned p = packed[s0 + i];
    int idx = atomicAdd(&cur[p & 127u], 1);
    sortedSrc[idx] = (int)(p >> 7);
  }
}

// ===========================================================================
// Weight prep: W[K][N] fp32 -> transposed bf16 hi/lo planes [N][K].
// ===========================================================================
__global__ __launch_bounds__(256) void wprep_k(
    const float* __restrict__ W, unsigned short* __restrict__ th,
    unsigned short* __restrict__ tl, int K, int N) {
  int i = blockIdx.x * blockDim.x + threadIdx.x;
  if (i < K * N) {
    int k = i / N, n = i % N;
    float v = W[i];
    unsigned short h = f2bf(v);
    unsigned short l = f2bf(v - bf2f(h));
    th[(long)n * K + k] = h;
    tl[(long)n * K + k] = l;
  }
}

// x fp32 -> bf16 hi plane (for the gather path)
__global__ __launch_bounds__(256) void xprep_k(const float* __restrict__ x,
                                               unsigned short* __restrict__ xh,
                                               int n) {
  int i = blockIdx.x * blockDim.x + threadIdx.x;
  if (i < n) xh[i] = f2bf(x[i]);
}

// ===========================================================================
// CSR gather-sum (bf16 rows) + GIN combine -> bf16 hi/lo planes.
//   Processes a 128-channel slice [off, off+128) of rows with stride S.
//   res = (1+eps)*self[n] + sum_{in-edges} bf2f(feat_h[src])
//   XF32: self from fp32 xf; else self = bf2f(xh)+bf2f(xl) (hi/lo planes).
// One wave per node; lane holds 2 channels (ushort2 gathers, 256B/row slice).
// Inner loop: 8 independent row-gathers in flight per round (latency hiding).
// ===========================================================================
template <bool XF32>
__global__ __launch_bounds__(256) void agg_s_k(
    const unsigned short* __restrict__ feat_h, const float* __restrict__ xf,
    const unsigned short* __restrict__ xh, const unsigned short* __restrict__ xl,
    const float* __restrict__ epsp, const int* __restrict__ rowEnd,
    const int* __restrict__ sortedSrc, unsigned short* __restrict__ oh,
    unsigned short* __restrict__ ol, int M, int S, int off) {
  constexpr int V = 2;
  const int lane = threadIdx.x & 63;
  const int w = (int)((blockIdx.x * blockDim.x + threadIdx.x) >> 6);
  if (w >= M) return;
  const int start = w ? rowEnd[w - 1] : 0;
  const int end = rowEnd[w];
  const int c0 = lane * V + off;

  float acc[V] = {};
  int e = start;
  // 8-deep gather window: issue all 8 loads before consuming any.
  for (; e + 8 <= end; e += 8) {
    int si[8];
#pragma unroll
    for (int q = 0; q < 8; ++q) si[q] = sortedSrc[e + q];
    ushort2 t[8];
#pragma unroll
    for (int q = 0; q < 8; ++q)
      t[q] = *(const ushort2*)(feat_h + (long)si[q] * S + c0);
#pragma unroll
    for (int q = 0; q < 8; ++q) {
      acc[0] += bf2f(t[q].x);
      acc[1] += bf2f(t[q].y);
    }
  }
  for (; e + 4 <= end; e += 4) {
    int s0 = sortedSrc[e + 0];
    int s1 = sortedSrc[e + 1];
    int s2 = sortedSrc[e + 2];
    int s3 = sortedSrc[e + 3];
    ushort2 a = *(const ushort2*)(feat_h + (long)s0 * S + c0);
    ushort2 b = *(const ushort2*)(feat_h + (long)s1 * S + c0);
    ushort2 c = *(const ushort2*)(feat_h + (long)s2 * S + c0);
    ushort2 d = *(const ushort2*)(feat_h + (long)s3 * S + c0);
    acc[0] += bf2f(a.x) + bf2f(b.x) + bf2f(c.x) + bf2f(d.x);
    acc[1] += bf2f(a.y) + bf2f(b.y) + bf2f(c.y) + bf2f(d.y);
  }
  for (; e < end; ++e) {
    ushort2 a = *(const ushort2*)(feat_h + (long)sortedSrc[e] * S + c0);
    acc[0] += bf2f(a.x);
    acc[1] += bf2f(a.y);
  }

  const float s = 1.0f + epsp[0];
  float xv[V];
  if constexpr (XF32) {
#pragma unroll
    for (int v = 0; v < V; ++v) xv[v] = xf[(long)w * S + c0 + v];
  } else {
#pragma unroll
    for (int v = 0; v < V; ++v)
      xv[v] = bf2f(xh[(long)w * S + c0 + v]) + bf2f(xl[(long)w * S + c0 + v]);
  }

  unsigned short hv[V], lv[V];
#pragma unroll
  for (int v = 0; v < V; ++v) {
    float res = fmaf(s, xv[v], acc[v]);
    hv[v] = f2bf(res);
    lv[v] = f2bf(res - bf2f(hv[v]));
  }
  *(ushort2*)&oh[(long)w * S + c0] = make_ushort2(hv[0], hv[1]);
  *(ushort2*)&ol[(long)w * S + c0] = make_ushort2(lv[0], lv[1]);
}

// ===========================================================================
// Split-bf16 MFMA GEMM, full-N blocks, 2-phase double-buffered staging:
//   Block = 64 rows x N (N = NFRAG*16). 4 waves; wave = 16-row m-frag x NFRAG.
//   Per K-iter (BK=32): issue STAGE(next buf) BEFORE ds_read+MFMA(cur buf);
//   single __syncthreads (vmcnt drain) per iter -> staging latency hides
//   under the current tile's MFMA. 3-pass split MFMA (hh, hl, lh).
// ===========================================================================
template <int NFRAG, bool RELU, bool HILO, int MINW>
__global__ __launch_bounds__(256, MINW) void gemm_wide_k(
    const unsigned short* __restrict__ Ah, const unsigned short* __restrict__ Al,
    const unsigned short* __restrict__ Bth, const unsigned short* __restrict__ Btl,
    const float* __restrict__ bias, float* __restrict__ outf,
    unsigned short* __restrict__ oh, unsigned short* __restrict__ ol,
    int M, int K) {
  constexpr int N = NFRAG * 16;
  __shared__ unsigned short Ahs[2][64 * 32];
  __shared__ unsigned short Als[2][64 * 32];
  __shared__ unsigned short Bhs[2][N * 32];
  __shared__ unsigned short Bls[2][N * 32];

  const int tid = threadIdx.x;
  const int lane = tid & 63;
  const int wave = tid >> 6;
  const int l15 = lane & 15;
  const int quad = lane >> 4;
  const int m0 = blockIdx.x * 64;

  float4e acc[NFRAG];
#pragma unroll
  for (int j = 0; j < NFRAG; ++j) acc[j] = 0.0f;

  const int a_row = tid >> 2;
  const int a_col = (tid & 3) * 8;
  const bool a_ok = (m0 + a_row) < M;

  auto stage = [&](int buf, int k0) {
    long ga = (long)(m0 + a_row) * K + k0 + a_col;
    if (a_ok) {
      GLDS16(Ah + ga, &Ahs[buf][tid * 8]);
      GLDS16(Al + ga, &Als[buf][tid * 8]);
    }
#pragma unroll
    for (int u = 0; u < NFRAG / 4; ++u) {
      int c = u * 256 + tid;
      long gb = (long)(c >> 2) * K + k0 + (c & 3) * 8;
      GLDS16(Bth + gb, &Bhs[buf][c * 8]);
      GLDS16(Btl + gb, &Bls[buf][c * 8]);
    }
  };

  const int nt = K >> 5;
  stage(0, 0);
  __syncthreads();

  for (int t = 0; t < nt; ++t) {
    const int cur = t & 1;
    if (t + 1 < nt) stage(cur ^ 1, (t + 1) * 32);  // prefetch next tile

    short8 a_h = *(const short8*)&Ahs[cur][(wave * 16 + l15) * 32 + quad * 8];
    short8 a_l = *(const short8*)&Als[cur][(wave * 16 + l15) * 32 + quad * 8];

#pragma unroll
    for (int j = 0; j < NFRAG; ++j) {
      short8 b_h = *(const short8*)&Bhs[cur][(j * 16 + l15) * 32 + quad * 8];
      short8 b_l = *(const short8*)&Bls[cur][(j * 16 + l15) * 32 + quad * 8];
      acc[j] = __builtin_amdgcn_mfma_f32_16x16x32_bf16(a_h, b_h, acc[j], 0, 0, 0);
      acc[j] = __builtin_amdgcn_mfma_f32_16x16x32_bf16(a_h, b_l, acc[j], 0, 0, 0);
      acc[j] = __builtin_amdgcn_mfma_f32_16x16x32_bf16(a_l, b_h, acc[j], 0, 0, 0);
    }
    __syncthreads();  // drains prefetch vmcnt + guards buffer reuse
  }

#pragma unroll
  for (int j = 0; j < NFRAG; ++j) {
    int col = j * 16 + l15;
    float bj = bias[col];
    int rbase = m0 + wave * 16 + quad * 4;
#pragma unroll
    for (int r = 0; r < 4; ++r) {
      int row = rbase + r;
      if (row < M) {
        float v = acc[j][r] + bj;
        if constexpr (RELU) v = fmaxf(v, 0.0f);
        if constexpr (HILO) {
          unsigned short h = f2bf(v);
          oh[(long)row * N + col] = h;
          ol[(long)row * N + col] = f2bf(v - bf2f(h));
        } else {
          outf[(long)row * N + col] = v;
        }
      }
    }
  }
}

extern "C" void kernel_launch(void* const* d_in, const int* in_sizes, int n_in,
                              void* d_out, int out_size, void* d_ws, size_t ws_size,
                              hipStream_t stream) {
  const float* x    = (const float*)d_in[0];
  const int*   ei   = (const int*)d_in[1];
  const float* eps1 = (const float*)d_in[2];
  const float* W1a  = (const float*)d_in[3];
  const float* b1a  = (const float*)d_in[4];
  const float* W1b  = (const float*)d_in[5];
  const float* b1b  = (const float*)d_in[6];
  const float* eps2 = (const float*)d_in[7];
  const float* W2a  = (const float*)d_in[8];
  const float* b2a  = (const float*)d_in[9];
  const float* W2b  = (const float*)d_in[10];
  const float* b2b  = (const float*)d_in[11];
  float* out = (float*)d_out;

  const int* srcp = ei;
  const int* dstp = ei + N_EDGES;

  // ---- workspace: two 102.4MB halves, cycled ----
  char* ws = (char*)d_ws;
  const size_t SZ = (size_t)N_NODES * 256 * sizeof(float);  // 102.4 MB
  char* P1 = ws;
  char* P2 = ws + SZ;

  // P1 phase A: C1 hilo [M][128] (51.2MB) + xh [M][128] bf16 (25.6MB)
  unsigned short* C1h = (unsigned short*)P1;
  unsigned short* C1l = C1h + (size_t)N_NODES * 128;
  unsigned short* xh  = C1l + (size_t)N_NODES * 128;
  // P2 phase A: T1 hilo [M][256] (102.4MB)
  unsigned short* T1h = (unsigned short*)P2;
  unsigned short* T1l = T1h + (size_t)N_NODES * 256;
  // P1 phase B: H hilo [M][256] (102.4MB)  (C1/xh dead)
  unsigned short* Hh = (unsigned short*)P1;
  unsigned short* Hl = Hh + (size_t)N_NODES * 256;
  // P2 phase B: C2 hilo [M][256]  (T1 dead)
  unsigned short* C2h = (unsigned short*)P2;
  unsigned short* C2l = C2h + (size_t)N_NODES * 256;
  // P1 phase C: T2 hilo [M][256]  (H dead)
  unsigned short* T2h = (unsigned short*)P1;
  unsigned short* T2l = T2h + (size_t)N_NODES * 256;
  // P2 phase C: W2b planes (C2 dead)
  unsigned short* W2bh = (unsigned short*)P2;
  unsigned short* W2bl = W2bh + 128 * 256;

  // ---- d_out scratch: CSR + early weight planes (dead before final GEMM) ----
  char* ob = (char*)d_out;
  int* rowEnd    = (int*)(ob + 400 * 1024);
  int* sortedSrc = (int*)(ob + 800 * 1024);
  size_t wofs = 7340032;
  unsigned short* W1ah = (unsigned short*)(ob + wofs);
  unsigned short* W1al = W1ah + 256 * 128;
  unsigned short* W1bh = (unsigned short*)(ob + wofs + 2 * 65536);
  unsigned short* W1bl = W1bh + 256 * 256;
  unsigned short* W2ah = (unsigned short*)(ob + wofs + 2 * 65536 + 2 * 131072);
  unsigned short* W2al = W2ah + 256 * 256;
  // packed edges + padded bucket arrays in the high region (all dead pre-final-GEMM)
  unsigned int* packed = (unsigned int*)(ob + 16 * 1024 * 1024);         // 6.4MB
  int* bucketCnt    = (int*)(ob + 24 * 1024 * 1024);  // NB*BSTRIDE ints (100KB)
  int* bucketCursor = (int*)(ob + 26 * 1024 * 1024);  // NB*BSTRIDE ints (100KB)
  int* bucketStart  = (int*)(ob + 28 * 1024 * 1024);  // NB+1 ints

  dim3 blk(256);
  dim3 gEdges((N_EDGES + 255) / 256);
  dim3 gAgg((N_NODES + 3) / 4);
  dim3 gGemm((N_NODES + 63) / 64);
  dim3 gW1((128 * 256 + 255) / 256);
  dim3 gW2((256 * 256 + 255) / 256);
  dim3 gXp((N_NODES * 128 + 255) / 256);

  // ---- bucketed CSR build + weight/x prep ----
  hipMemsetAsync(bucketCnt, 0, NB * BSTRIDE * sizeof(int), stream);
  bucketHist_k<<<dim3(512), blk, 0, stream>>>(dstp, bucketCnt, N_EDGES);
  scanB_k<<<1, dim3(1024), 0, stream>>>(bucketCnt, bucketStart, bucketCursor);
  bucketScatter_k<<<gEdges, blk, 0, stream>>>(srcp, dstp, bucketCursor, packed,
                                              N_EDGES);
  fillB_k<<<dim3(NB), blk, 0, stream>>>(bucketStart, packed, rowEnd, sortedSrc,
                                        N_NODES);
  xprep_k<<<gXp, blk, 0, stream>>>(x, xh, N_NODES * 128);
  wprep_k<<<gW1, blk, 0, stream>>>(W1a, W1ah, W1al, 128, 256);
  wprep_k<<<gW2, blk, 0, stream>>>(W1b, W1bh, W1bl, 256, 256);
  wprep_k<<<gW2, blk, 0, stream>>>(W2a, W2ah, W2al, 256, 256);

  // ---- Layer 1 ----
  agg_s_k<true><<<gAgg, blk, 0, stream>>>(
      xh, x, nullptr, nullptr, eps1, rowEnd, sortedSrc, C1h, C1l, N_NODES, 128, 0);
  gemm_wide_k<16, true, true, 2><<<gGemm, blk, 0, stream>>>(
      C1h, C1l, W1ah, W1al, b1a, nullptr, T1h, T1l, N_NODES, 128);
  gemm_wide_k<16, true, true, 2><<<gGemm, blk, 0, stream>>>(
      T1h, T1l, W1bh, W1bl, b1b, nullptr, Hh, Hl, N_NODES, 256);  // h as hilo

  // ---- Layer 2 ----
  agg_s_k<false><<<gAgg, blk, 0, stream>>>(
      Hh, nullptr, Hh, Hl, eps2, rowEnd, sortedSrc, C2h, C2l, N_NODES, 256, 0);
  agg_s_k<false><<<gAgg, blk, 0, stream>>>(
      Hh, nullptr, Hh, Hl, eps2, rowEnd, sortedSrc, C2h, C2l, N_NODES, 256, 128);
  gemm_wide_k<16, true, true, 2><<<gGemm, blk, 0, stream>>>(
      C2h, C2l, W2ah, W2al, b2a, nullptr, T2h, T2l, N_NODES, 256);
  wprep_k<<<gW1, blk, 0, stream>>>(W2b, W2bh, W2bl, 256, 128);  // C2 dead now
  gemm_wide_k<8, false, false, 3><<<gGemm, blk, 0, stream>>>(
      T2h, T2l, W2bh, W2bl, b2b, out, nullptr, nullptr, N_NODES, 256);
}

// Round 6
// 662.744 us; speedup vs baseline: 1.2472x; 1.2472x over previous
//
#include <hip/hip_runtime.h>

#define N_NODES 100000
#define N_EDGES 1600000
#define NB 782       // ceil(N_NODES/128) buckets of 128 dst nodes
#define SC_BLK 256   // blocks in the binning passes (blockHist is [NB][SC_BLK])

typedef __attribute__((ext_vector_type(8))) short short8;
typedef __attribute__((ext_vector_type(4))) float float4e;

// async 16B global->LDS copy (lane-contiguous LDS dest)
#define GLDS16(g, l)                                                   \
  __builtin_amdgcn_global_load_lds(                                    \
      (const __attribute__((address_space(1))) unsigned int*)(g),      \
      (__attribute__((address_space(3))) unsigned int*)(l), 16, 0, 0)

// ---------------------------------------------------------------------------
// bf16 split helpers (RNE)
// ---------------------------------------------------------------------------
__device__ __forceinline__ unsigned short f2bf(float f) {
  unsigned u = __float_as_uint(f);
  u += 0x7FFFu + ((u >> 16) & 1u);
  return (unsigned short)(u >> 16);
}
__device__ __forceinline__ float bf2f(unsigned short h) {
  return __uint_as_float(((unsigned)h) << 16);
}

// ===========================================================================
// CSR build, zero global atomics (scratch in d_out, dead before final GEMM).
//   bucket b = dst >> 7 (128 nodes). packed edge = (src<<7)|(dst&127).
//   Pass 1: per-block LDS hist -> blockHist[b][blk]
//   Pass 2: wave-per-bucket scan over blocks; Pass 3: bucket scan ->
//   bucketStart; Pass 4: scatter with LDS cursors (deterministic offsets).
// ===========================================================================
__global__ __launch_bounds__(256) void histA_k(const int* __restrict__ dst,
                                               int* __restrict__ bh, int nE) {
  __shared__ int h[NB];
  const int blk = blockIdx.x, tid = threadIdx.x;
  for (int b = tid; b < NB; b += 256) h[b] = 0;
  __syncthreads();
  const int epb = (nE + SC_BLK - 1) / SC_BLK;
  const int i1 = min(blk * epb + epb, nE);
  for (int i = blk * epb + tid; i < i1; i += 256)
    atomicAdd(&h[dst[i] >> 7], 1);
  __syncthreads();
  for (int b = tid; b < NB; b += 256) bh[b * SC_BLK + blk] = h[b];
}

// one wave per bucket: exclusive scan of 256 block counts (4/lane + shfl_up)
__global__ __launch_bounds__(256) void scanW_k(int* __restrict__ bh,
                                               int* __restrict__ tot) {
  const int b = blockIdx.x * 4 + (threadIdx.x >> 6);
  const int lane = threadIdx.x & 63;
  if (b >= NB) return;
  const int base = b * SC_BLK + lane * 4;
  int v[4];
#pragma unroll
  for (int j = 0; j < 4; ++j) v[j] = bh[base + j];
  int ls = v[0] + v[1] + v[2] + v[3];
  int x = ls;
  for (int off = 1; off < 64; off <<= 1) {
    int y = __shfl_up(x, off);
    if (lane >= off) x += y;
  }
  int run = x - ls;  // exclusive prefix of this lane's 4-group
#pragma unroll
  for (int j = 0; j < 4; ++j) {
    int t = v[j];
    bh[base + j] = run;
    run += t;
  }
  if (lane == 63) tot[b] = run;  // inclusive total of bucket
}

__global__ __launch_bounds__(1024) void scanB2_k(const int* __restrict__ tot,
                                                 int* __restrict__ bucketStart) {
  __shared__ int sm[1024];
  const int tid = threadIdx.x;
  int v = (tid < NB) ? tot[tid] : 0;
  sm[tid] = v;
  __syncthreads();
  for (int off = 1; off < 1024; off <<= 1) {
    int t = (tid >= off) ? sm[tid - off] : 0;
    __syncthreads();
    sm[tid] += t;
    __syncthreads();
  }
  if (tid < NB) bucketStart[tid] = sm[tid] - v;
  if (tid == NB - 1) bucketStart[NB] = sm[tid];
}

__global__ __launch_bounds__(256) void scatter2_k(
    const int* __restrict__ src, const int* __restrict__ dst,
    const int* __restrict__ bucketStart, const int* __restrict__ bh,
    unsigned int* __restrict__ packed, int nE) {
  __shared__ int cur[NB];
  const int blk = blockIdx.x, tid = threadIdx.x;
  for (int b = tid; b < NB; b += 256)
    cur[b] = bucketStart[b] + bh[b * SC_BLK + blk];
  __syncthreads();
  const int epb = (nE + SC_BLK - 1) / SC_BLK;
  const int i1 = min(blk * epb + epb, nE);
  for (int i = blk * epb + tid; i < i1; i += 256) {
    int d = dst[i];
    int s = src[i];
    int p = atomicAdd(&cur[d >> 7], 1);  // LDS atomic only
    packed[p] = ((unsigned)s << 7) | (unsigned)(d & 127);
  }
}

// one block per bucket: LDS node-count + local scan -> rowEnd; LDS-cursor
// scatter of sortedSrc confined to this bucket's contiguous CSR range.
__global__ __launch_bounds__(256) void fillB_k(
    const int* __restrict__ bucketStart, const unsigned int* __restrict__ packed,
    int* __restrict__ rowEnd, int* __restrict__ sortedSrc, int nNodes) {
  __shared__ int cnt[128];
  __shared__ int cur[128];
  const int b = blockIdx.x;
  const int tid = threadIdx.x;
  const int s0 = bucketStart[b];
  const int ne = bucketStart[b + 1] - s0;
  if (tid < 128) cnt[tid] = 0;
  __syncthreads();
  for (int i = tid; i < ne; i += 256)
    atomicAdd(&cnt[packed[s0 + i] & 127u], 1);
  __syncthreads();
  int v = (tid < 128) ? cnt[tid] : 0;
  for (int off = 1; off < 128; off <<= 1) {
    int t = (tid < 128 && tid >= off) ? cnt[tid - off] : 0;
    __syncthreads();
    if (tid < 128) cnt[tid] += t;
    __syncthreads();
  }
  if (tid < 128) {
    cur[tid] = s0 + cnt[tid] - v;
    int node = b * 128 + tid;
    if (node < nNodes) rowEnd[node] = s0 + cnt[tid];
  }
  __syncthreads();
  for (int i = tid; i < ne; i += 256) {
    unsigned p = packed[s0 + i];
    int idx = atomicAdd(&cur[p & 127u], 1);
    sortedSrc[idx] = (int)(p >> 7);
  }
}

// ===========================================================================
// Weight prep: W[K][N] fp32 -> transposed bf16 hi/lo planes [N][K].
// ===========================================================================
__global__ __launch_bounds__(256) void wprep_k(
    const float* __restrict__ W, unsigned short* __restrict__ th,
    unsigned short* __restrict__ tl, int K, int N) {
  int i = blockIdx.x * blockDim.x + threadIdx.x;
  if (i < K * N) {
    int k = i / N, n = i % N;
    float v = W[i];
    unsigned short h = f2bf(v);
    unsigned short l = f2bf(v - bf2f(h));
    th[(long)n * K + k] = h;
    tl[(long)n * K + k] = l;
  }
}

// x fp32 -> bf16 hi plane (for the gather path)
__global__ __launch_bounds__(256) void xprep_k(const float* __restrict__ x,
                                               unsigned short* __restrict__ xh,
                                               int n) {
  int i = blockIdx.x * blockDim.x + threadIdx.x;
  if (i < n) xh[i] = f2bf(x[i]);
}

// ===========================================================================
// CSR gather-sum (bf16 rows) + GIN combine -> bf16 hi/lo planes.
//   Processes a 128-channel slice [off, off+128) of rows with stride S.
// One wave per node; lane holds 2 channels; 8-deep gather window.
// ===========================================================================
template <bool XF32>
__global__ __launch_bounds__(256) void agg_s_k(
    const unsigned short* __restrict__ feat_h, const float* __restrict__ xf,
    const unsigned short* __restrict__ xh, const unsigned short* __restrict__ xl,
    const float* __restrict__ epsp, const int* __restrict__ rowEnd,
    const int* __restrict__ sortedSrc, unsigned short* __restrict__ oh,
    unsigned short* __restrict__ ol, int M, int S, int off) {
  constexpr int V = 2;
  const int lane = threadIdx.x & 63;
  const int w = (int)((blockIdx.x * blockDim.x + threadIdx.x) >> 6);
  if (w >= M) return;
  const int start = w ? rowEnd[w - 1] : 0;
  const int end = rowEnd[w];
  const int c0 = lane * V + off;

  float acc[V] = {};
  int e = start;
  for (; e + 8 <= end; e += 8) {
    int si[8];
#pragma unroll
    for (int q = 0; q < 8; ++q) si[q] = sortedSrc[e + q];
    ushort2 t[8];
#pragma unroll
    for (int q = 0; q < 8; ++q)
      t[q] = *(const ushort2*)(feat_h + (long)si[q] * S + c0);
#pragma unroll
    for (int q = 0; q < 8; ++q) {
      acc[0] += bf2f(t[q].x);
      acc[1] += bf2f(t[q].y);
    }
  }
  for (; e + 4 <= end; e += 4) {
    int s0 = sortedSrc[e + 0];
    int s1 = sortedSrc[e + 1];
    int s2 = sortedSrc[e + 2];
    int s3 = sortedSrc[e + 3];
    ushort2 a = *(const ushort2*)(feat_h + (long)s0 * S + c0);
    ushort2 b = *(const ushort2*)(feat_h + (long)s1 * S + c0);
    ushort2 c = *(const ushort2*)(feat_h + (long)s2 * S + c0);
    ushort2 d = *(const ushort2*)(feat_h + (long)s3 * S + c0);
    acc[0] += bf2f(a.x) + bf2f(b.x) + bf2f(c.x) + bf2f(d.x);
    acc[1] += bf2f(a.y) + bf2f(b.y) + bf2f(c.y) + bf2f(d.y);
  }
  for (; e < end; ++e) {
    ushort2 a = *(const ushort2*)(feat_h + (long)sortedSrc[e] * S + c0);
    acc[0] += bf2f(a.x);
    acc[1] += bf2f(a.y);
  }

  const float s = 1.0f + epsp[0];
  float xv[V];
  if constexpr (XF32) {
#pragma unroll
    for (int v = 0; v < V; ++v) xv[v] = xf[(long)w * S + c0 + v];
  } else {
#pragma unroll
    for (int v = 0; v < V; ++v)
      xv[v] = bf2f(xh[(long)w * S + c0 + v]) + bf2f(xl[(long)w * S + c0 + v]);
  }

  unsigned short hv[V], lv[V];
#pragma unroll
  for (int v = 0; v < V; ++v) {
    float res = fmaf(s, xv[v], acc[v]);
    hv[v] = f2bf(res);
    lv[v] = f2bf(res - bf2f(hv[v]));
  }
  *(ushort2*)&oh[(long)w * S + c0] = make_ushort2(hv[0], hv[1]);
  *(ushort2*)&ol[(long)w * S + c0] = make_ushort2(lv[0], lv[1]);
}

// ===========================================================================
// Split-bf16 MFMA GEMM, m97-geometry: 128x128 tile, 4 waves (2x2), each wave
// 64x64 = acc[4][4]. Per BK=32: 16 ds_read_b128 vs 48 MFMA (3:1). LDS 32KB
// single-buffered. Bank-conflict fix: XOR swizzle P = L ^ (((L>>7)&7)<<4)
// (involution, bits>=7 untouched): staging loads inverse-swizzled GLOBAL
// source into linear LDS dest (global_load_lds constraint), reads apply the
// same XOR -> max 2-way (free).
// ===========================================================================
__device__ __forceinline__ short8 lds_rd(const unsigned short* base, int r,
                                         int q) {
  int L = r * 64 + q * 16;
  int P = L ^ (((L >> 7) & 7) << 4);
  return *(const short8*)((const char*)base + P);
}

template <bool RELU, bool HILO>
__global__ __launch_bounds__(256, 2) void gemm128_k(
    const unsigned short* __restrict__ Ah, const unsigned short* __restrict__ Al,
    const unsigned short* __restrict__ Bth, const unsigned short* __restrict__ Btl,
    const float* __restrict__ bias, float* __restrict__ outf,
    unsigned short* __restrict__ oh, unsigned short* __restrict__ ol,
    int M, int K, int NOUT) {
  __shared__ unsigned short Ash[128 * 32];
  __shared__ unsigned short Asl[128 * 32];
  __shared__ unsigned short Bsh[128 * 32];
  __shared__ unsigned short Bsl[128 * 32];

  const int tid = threadIdx.x;
  const int lane = tid & 63;
  const int wave = tid >> 6;
  const int l15 = lane & 15;
  const int quad = lane >> 4;
  const int wm = wave >> 1;
  const int wn = wave & 1;
  const int m0 = blockIdx.x * 128;
  const int n0 = blockIdx.y * 128;

  float4e acc[4][4];
#pragma unroll
  for (int i = 0; i < 4; ++i)
#pragma unroll
    for (int j = 0; j < 4; ++j) acc[i][j] = 0.0f;

  for (int k0 = 0; k0 < K; k0 += 32) {
    // stage: physical chunk c -> logical (row, quad) via involutive swizzle
#pragma unroll
    for (int h = 0; h < 2; ++h) {
      int c = h * 256 + tid;                  // 0..511 (16B chunks per plane)
      int P = c * 16;                         // physical byte offset
      int L = P ^ (((P >> 7) & 7) << 4);      // logical byte offset
      int r = L >> 6;
      int q = (L >> 4) & 3;
      if (m0 + r < M) {
        long ga = (long)(m0 + r) * K + k0 + q * 8;
        GLDS16(Ah + ga, Ash + c * 8);
        GLDS16(Al + ga, Asl + c * 8);
      }
      long gb = (long)(n0 + r) * K + k0 + q * 8;
      GLDS16(Bth + gb, Bsh + c * 8);
      GLDS16(Btl + gb, Bsl + c * 8);
    }
    __syncthreads();

    short8 ah[4], al[4];
#pragma unroll
    for (int mi = 0; mi < 4; ++mi) {
      ah[mi] = lds_rd(Ash, wm * 64 + mi * 16 + l15, quad);
      al[mi] = lds_rd(Asl, wm * 64 + mi * 16 + l15, quad);
    }
#pragma unroll
    for (int ni = 0; ni < 4; ++ni) {
      short8 bh = lds_rd(Bsh, wn * 64 + ni * 16 + l15, quad);
      short8 bl = lds_rd(Bsl, wn * 64 + ni * 16 + l15, quad);
#pragma unroll
      for (int mi = 0; mi < 4; ++mi) {
        acc[mi][ni] =
            __builtin_amdgcn_mfma_f32_16x16x32_bf16(ah[mi], bh, acc[mi][ni], 0, 0, 0);
        acc[mi][ni] =
            __builtin_amdgcn_mfma_f32_16x16x32_bf16(ah[mi], bl, acc[mi][ni], 0, 0, 0);
        acc[mi][ni] =
            __builtin_amdgcn_mfma_f32_16x16x32_bf16(al[mi], bh, acc[mi][ni], 0, 0, 0);
      }
    }
    __syncthreads();
  }

#pragma unroll
  for (int mi = 0; mi < 4; ++mi) {
#pragma unroll
    for (int ni = 0; ni < 4; ++ni) {
      int col = n0 + wn * 64 + ni * 16 + l15;
      float bj = bias[col];
      int rbase = m0 + wm * 64 + mi * 16 + quad * 4;
#pragma unroll
      for (int r = 0; r < 4; ++r) {
        int row = rbase + r;
        if (row < M) {
          float v = acc[mi][ni][r] + bj;
          if constexpr (RELU) v = fmaxf(v, 0.0f);
          if constexpr (HILO) {
            unsigned short h = f2bf(v);
            oh[(long)row * NOUT + col] = h;
            ol[(long)row * NOUT + col] = f2bf(v - bf2f(h));
          } else {
            outf[(long)row * NOUT + col] = v;
          }
        }
      }
    }
  }
}

extern "C" void kernel_launch(void* const* d_in, const int* in_sizes, int n_in,
                              void* d_out, int out_size, void* d_ws, size_t ws_size,
                              hipStream_t stream) {
  const float* x    = (const float*)d_in[0];
  const int*   ei   = (const int*)d_in[1];
  const float* eps1 = (const float*)d_in[2];
  const float* W1a  = (const float*)d_in[3];
  const float* b1a  = (const float*)d_in[4];
  const float* W1b  = (const float*)d_in[5];
  const float* b1b  = (const float*)d_in[6];
  const float* eps2 = (const float*)d_in[7];
  const float* W2a  = (const float*)d_in[8];
  const float* b2a  = (const float*)d_in[9];
  const float* W2b  = (const float*)d_in[10];
  const float* b2b  = (const float*)d_in[11];
  float* out = (float*)d_out;

  const int* srcp = ei;
  const int* dstp = ei + N_EDGES;

  // ---- workspace: two 102.4MB halves, cycled ----
  char* ws = (char*)d_ws;
  const size_t SZ = (size_t)N_NODES * 256 * sizeof(float);  // 102.4 MB
  char* P1 = ws;
  char* P2 = ws + SZ;

  unsigned short* C1h = (unsigned short*)P1;
  unsigned short* C1l = C1h + (size_t)N_NODES * 128;
  unsigned short* xh  = C1l + (size_t)N_NODES * 128;
  unsigned short* T1h = (unsigned short*)P2;
  unsigned short* T1l = T1h + (size_t)N_NODES * 256;
  unsigned short* Hh = (unsigned short*)P1;
  unsigned short* Hl = Hh + (size_t)N_NODES * 256;
  unsigned short* C2h = (unsigned short*)P2;
  unsigned short* C2l = C2h + (size_t)N_NODES * 256;
  unsigned short* T2h = (unsigned short*)P1;
  unsigned short* T2l = T2h + (size_t)N_NODES * 256;
  unsigned short* W2bh = (unsigned short*)P2;
  unsigned short* W2bl = W2bh + 128 * 256;

  // ---- d_out scratch (all dead before final GEMM overwrites d_out) ----
  char* ob = (char*)d_out;
  int* rowEnd    = (int*)(ob + 400 * 1024);
  int* sortedSrc = (int*)(ob + 800 * 1024);
  size_t wofs = 7340032;
  unsigned short* W1ah = (unsigned short*)(ob + wofs);
  unsigned short* W1al = W1ah + 256 * 128;
  unsigned short* W1bh = (unsigned short*)(ob + wofs + 2 * 65536);
  unsigned short* W1bl = W1bh + 256 * 256;
  unsigned short* W2ah = (unsigned short*)(ob + wofs + 2 * 65536 + 2 * 131072);
  unsigned short* W2al = W2ah + 256 * 256;
  unsigned int* packed = (unsigned int*)(ob + 16 * 1024 * 1024);   // 6.4MB
  int* bucketStart = (int*)(ob + 28 * 1024 * 1024);                // NB+1 ints
  int* bucketTot   = (int*)(ob + 28 * 1024 * 1024 + 8192);         // NB ints
  int* blockHist   = (int*)(ob + 30 * 1024 * 1024);                // NB*SC_BLK ints

  dim3 blk(256);
  dim3 gAgg((N_NODES + 3) / 4);
  dim3 gW1((128 * 256 + 255) / 256);
  dim3 gW2((256 * 256 + 255) / 256);
  dim3 gXp((N_NODES * 128 + 255) / 256);
  dim3 gGemm2((N_NODES + 127) / 128, 2);   // N=256 outputs
  dim3 gGemm1((N_NODES + 127) / 128, 1);   // N=128 output

  // ---- CSR build (no global atomics) + weight/x prep ----
  histA_k<<<dim3(SC_BLK), blk, 0, stream>>>(dstp, blockHist, N_EDGES);
  scanW_k<<<dim3((NB + 3) / 4), blk, 0, stream>>>(blockHist, bucketTot);
  scanB2_k<<<1, dim3(1024), 0, stream>>>(bucketTot, bucketStart);
  scatter2_k<<<dim3(SC_BLK), blk, 0, stream>>>(srcp, dstp, bucketStart,
                                               blockHist, packed, N_EDGES);
  fillB_k<<<dim3(NB), blk, 0, stream>>>(bucketStart, packed, rowEnd, sortedSrc,
                                        N_NODES);
  xprep_k<<<gXp, blk, 0, stream>>>(x, xh, N_NODES * 128);
  wprep_k<<<gW1, blk, 0, stream>>>(W1a, W1ah, W1al, 128, 256);
  wprep_k<<<gW2, blk, 0, stream>>>(W1b, W1bh, W1bl, 256, 256);
  wprep_k<<<gW2, blk, 0, stream>>>(W2a, W2ah, W2al, 256, 256);

  // ---- Layer 1 ----
  agg_s_k<true><<<gAgg, blk, 0, stream>>>(
      xh, x, nullptr, nullptr, eps1, rowEnd, sortedSrc, C1h, C1l, N_NODES, 128, 0);
  gemm128_k<true, true><<<gGemm2, blk, 0, stream>>>(
      C1h, C1l, W1ah, W1al, b1a, nullptr, T1h, T1l, N_NODES, 128, 256);
  gemm128_k<true, true><<<gGemm2, blk, 0, stream>>>(
      T1h, T1l, W1bh, W1bl, b1b, nullptr, Hh, Hl, N_NODES, 256, 256);

  // ---- Layer 2 ----
  agg_s_k<false><<<gAgg, blk, 0, stream>>>(
      Hh, nullptr, Hh, Hl, eps2, rowEnd, sortedSrc, C2h, C2l, N_NODES, 256, 0);
  agg_s_k<false><<<gAgg, blk, 0, stream>>>(
      Hh, nullptr, Hh, Hl, eps2, rowEnd, sortedSrc, C2h, C2l, N_NODES, 256, 128);
  gemm128_k<true, true><<<gGemm2, blk, 0, stream>>>(
      C2h, C2l, W2ah, W2al, b2a, nullptr, T2h, T2l, N_NODES, 256, 256);
  wprep_k<<<gW1, blk, 0, stream>>>(W2b, W2bh, W2bl, 256, 128);  // C2 dead now
  gemm128_k<false, false><<<gGemm1, blk, 0, stream>>>(
      T2h, T2l, W2bh, W2bl, b2b, out, nullptr, nullptr, N_NODES, 256, 128);
}